// Round 22
// baseline (80.928 us; speedup 1.0000x reference)
//
#include <hip/hip_runtime.h>

#define N_SP 3136   // H*W = 49*64
#define C_CH 256
#define CQ   32
#define NB   4
#define JT   64     // attn j-tile
#define NJT  49     // j-tiles (exact)
#define QT   64     // attn q-tile (49 tiles exact)
// 1 / (exp(sqrt(3))*sqrt(3136/256) + 2*sqrt(6))
#define INV_BOUND 0.04051569f
#define LOG2E 1.44269504f

typedef __attribute__((ext_vector_type(8))) short bf16x8;
typedef __attribute__((ext_vector_type(4))) float f32x4;
typedef __attribute__((ext_vector_type(2))) long long l64x2;
typedef unsigned short u16;
typedef unsigned int   u32;
typedef unsigned char  u8;
typedef long long      l64;
typedef unsigned long long u64;

#define MFMA16(a,b,c) __builtin_amdgcn_mfma_f32_16x16x32_bf16(a,b,c,0,0,0)
#define MFMA8(a,b,c)  __builtin_amdgcn_mfma_f32_16x16x32_bf8_fp8(a,b,c,0,0,0)

__device__ __forceinline__ u16 f2b(float f) {
    u32 u = __builtin_bit_cast(u32, f);
    u += 0x7fffu + ((u >> 16) & 1u);   // RTNE
    return (u16)(u >> 16);
}
__device__ __forceinline__ u8 f2fp8(float f) {
    return (u8)(__builtin_amdgcn_cvt_pk_fp8_f32(f, f, 0, false) & 0xff);
}
__device__ __forceinline__ void dma16(const void* g, void* l) {
    __builtin_amdgcn_global_load_lds((const __attribute__((address_space(1))) u32*)g,
                                     (__attribute__((address_space(3))) u32*)l, 16, 0, 0);
}
__device__ __forceinline__ void nt_store8(void* p, ushort4 v) {
    __builtin_nontemporal_store(__builtin_bit_cast(u64, v), (u64*)p);
}

// ---------------------------------------------------------------------------
// stage0: W->bf16 pre-swizzled (blocks 0..79), norm+scale+kmax0 (block 80)
// ---------------------------------------------------------------------------
__global__ __launch_bounds__(256) void stage0_kernel(
    const float* __restrict__ Wq, const float* __restrict__ Wk,
    const float* __restrict__ Wv, u8* __restrict__ Wqb,
    u8* __restrict__ Wkb, u8* __restrict__ Wvb,
    float* __restrict__ scale_out, float* __restrict__ kmax)
{
    __shared__ float red[256];
    const int t = threadIdx.x;
    const int bid = blockIdx.x;

    if (bid < 80) {
        int idx = bid * 256 + t;
        const float* src; u8* dst; int off;
        if (idx < 2048)      { src = Wq; dst = Wqb; off = idx; }
        else if (idx < 4096) { src = Wk; dst = Wkb; off = idx - 2048; }
        else                 { src = Wv; dst = Wvb; off = idx - 4096; }
        float4 v = *(const float4*)(src + off * 4);
        ushort4 o; o.x = f2b(v.x); o.y = f2b(v.y); o.z = f2b(v.z); o.w = f2b(v.w);
        const int row = off >> 6, inner = (off & 63) * 8;
        *(ushort4*)(dst + row * 512 + (inner ^ ((row & 15) << 5))) = o;
    } else {
        if (t < NB) kmax[t] = 0.f;
        float u2 = 0.f;
        for (int i = t; i < CQ * C_CH; i += 256) { float w = Wq[i]; u2 += w * w; }
        red[t] = u2; __syncthreads();
        #pragma unroll
        for (int s = 128; s > 0; s >>= 1) { if (t < s) red[t] += red[t + s]; __syncthreads(); }
        float u2t = red[0]; __syncthreads();
        float vn2 = 0.f;
        for (int o = 0; o < CQ; ++o)   { float w = Wk[o * C_CH + t]; vn2 += w * w; }
        float wn2 = 0.f;
        for (int o = 0; o < C_CH; ++o) { float w = Wv[o * C_CH + t]; wn2 += w * w; }
        red[t] = fmaxf(vn2, wn2); __syncthreads();
        #pragma unroll
        for (int s = 128; s > 0; s >>= 1) { if (t < s) red[t] = fmaxf(red[t], red[t + s]); __syncthreads(); }
        if (t == 0) scale_out[0] = 1.0f / (sqrtf(u2t) * sqrtf(red[0]));
    }
}

// ---------------------------------------------------------------------------
// qkv_fused (R21 structure; K/V/qT stores NON-TEMPORAL so attn reads come
// from clean L3 instead of dirty remote L2 -- the single R22 variable).
// ---------------------------------------------------------------------------
__global__ __launch_bounds__(1024) void qkv_fused(
    const float* __restrict__ x, const u8* __restrict__ Wqb,
    const u8* __restrict__ Wkb, const u8* __restrict__ Wvb,
    const float* __restrict__ bq, const float* __restrict__ bk,
    const float* __restrict__ bv, const float* __restrict__ scale_p,
    u16* __restrict__ qT, u8* __restrict__ Kg, u8* __restrict__ Vg,
    float* __restrict__ qnorm, float* __restrict__ kmax)
{
    __shared__ __align__(16) u8 smem[132096];
    u8* const xTl = smem;                          // 32768: [64n][512B] swizzled
    u8* const FW  = smem + 32768;                  // 66560: ftile[4] -> Wv half
    u8* const W0  = smem + 99328;                  // 32768: Wq|Wk

    const int t = threadIdx.x;
    const int w = t >> 6, lane = t & 63, li = t & 15, g = (t >> 4) & 3;
    const int wq = w & 3;
    const int b  = blockIdx.x / NJT;
    const int nt = blockIdx.x % NJT;
    const int n0 = nt * 64;
    const f32x4 zero = {0.f, 0.f, 0.f, 0.f};

    #pragma unroll
    for (int k = 0; k < 2; ++k)
        dma16((k == 0 ? Wqb : Wkb) + t * 16, W0 + k * 16384 + w * 1024);

    // ---- Phase A: transpose 4 slabs concurrently ----
    {
        const int sl = t >> 8, tt = t & 255;
        const int c0 = sl * 64;
        float* ftile = (float*)(FW + sl * 16640);  // [64][65]
        const int cc = tt >> 4, nn4 = (tt & 15) * 4;
        #pragma unroll
        for (int k = 0; k < 4; ++k) {
            int cl = cc + k * 16;
            float4 v = *(const float4*)(x + (size_t)(b * C_CH + c0 + cl) * N_SP + n0 + nn4);
            ftile[cl * 65 + nn4]     = v.x;
            ftile[cl * 65 + nn4 + 1] = v.y;
            ftile[cl * 65 + nn4 + 2] = v.z;
            ftile[cl * 65 + nn4 + 3] = v.w;
        }
        __syncthreads();
        const int c4 = (tt & 15) * 4, nn = tt >> 4;
        #pragma unroll
        for (int k = 0; k < 4; ++k) {
            int nl = nn + k * 16;
            ushort4 o;
            o.x = f2b(ftile[(c4 + 0) * 65 + nl]);
            o.y = f2b(ftile[(c4 + 1) * 65 + nl]);
            o.z = f2b(ftile[(c4 + 2) * 65 + nl]);
            o.w = f2b(ftile[(c4 + 3) * 65 + nl]);
            *(ushort4*)(xTl + nl * 512 + (((c0 + c4) * 2) ^ ((nl & 15) << 5))) = o;
        }
    }
    __syncthreads();                               // ftile dead; xTl complete

    #pragma unroll
    for (int k = 0; k < 4; ++k)
        dma16(Wvb + k * 16384 + t * 16, FW + k * 16384 + w * 1024);

    const int swz = li << 5;
    const int n = n0 + wq * 16 + li;
    bf16x8 xf[8];
    #pragma unroll
    for (int ks = 0; ks < 8; ++ks)
        xf[ks] = *(const bf16x8*)(xTl + (wq * 16 + li) * 512 + ((ks * 64 + 16 * g) ^ swz));

    asm volatile("s_waitcnt vmcnt(4) lgkmcnt(0)" ::: "memory");
    __builtin_amdgcn_s_barrier();
    asm volatile("" ::: "memory");

    const int wh = w >> 2;
    if (w < 8) {
        if (wh == 0) {
            f32x4 aq0 = zero, aq1 = zero;
            #pragma unroll
            for (int ks = 0; ks < 8; ++ks) {
                const int o = (ks * 64 + 16 * g) ^ swz;
                bf16x8 w0 = *(const bf16x8*)(W0 + li * 512 + o);
                bf16x8 w1 = *(const bf16x8*)(W0 + (16 + li) * 512 + o);
                aq0 = MFMA16(w0, xf[ks], aq0);
                aq1 = MFMA16(w1, xf[ks], aq1);
            }
            const float scf = scale_p[0] * LOG2E;
            f32x4 bq0 = *(const f32x4*)(bq + 4 * g);
            f32x4 bq1 = *(const f32x4*)(bq + 16 + 4 * g);
            float qn2 = 0.f;
            ushort4 s0, s1;
            #pragma unroll
            for (int r = 0; r < 4; ++r) {
                float q0 = (aq0[r] + bq0[r]) * scf;
                float q1 = (aq1[r] + bq1[r]) * scf;
                qn2 += q0 * q0 + q1 * q1;
                ((u16*)&s0)[r] = f2b(q0); ((u16*)&s1)[r] = f2b(q1);
            }
            nt_store8(qT + (size_t)(b * N_SP + n) * CQ + 4 * g, s0);
            nt_store8(qT + (size_t)(b * N_SP + n) * CQ + 16 + 4 * g, s1);
            qn2 += __shfl_xor(qn2, 16); qn2 += __shfl_xor(qn2, 32);
            if (g == 0) qnorm[b * N_SP + n] = sqrtf(qn2);
        } else {
            f32x4 ak0 = zero, ak1 = zero;
            #pragma unroll
            for (int ks = 0; ks < 8; ++ks) {
                const int o = (ks * 64 + 16 * g) ^ swz;
                bf16x8 w2 = *(const bf16x8*)(W0 + 16384 + li * 512 + o);
                bf16x8 w3 = *(const bf16x8*)(W0 + 16384 + (16 + li) * 512 + o);
                ak0 = MFMA16(w2, xf[ks], ak0);
                ak1 = MFMA16(w3, xf[ks], ak1);
            }
            f32x4 bk0 = *(const f32x4*)(bk + 4 * g);
            f32x4 bk1 = *(const f32x4*)(bk + 16 + 4 * g);
            float kn2 = 0.f;
            ushort4 s0, s1;
            #pragma unroll
            for (int r = 0; r < 4; ++r) {
                float k0 = ak0[r] + bk0[r];
                float k1 = ak1[r] + bk1[r];
                kn2 += k0 * k0 + k1 * k1;
                ((u16*)&s0)[r] = f2b(k0); ((u16*)&s1)[r] = f2b(k1);
            }
            u8* krow = Kg + ((size_t)b * N_SP + n) * 64;
            const int swn = ((n >> 1) & 3) << 4;
            nt_store8(krow + ((8 * g) ^ swn), s0);
            nt_store8(krow + ((32 + 8 * g) ^ swn), s1);
            kn2 += __shfl_xor(kn2, 16); kn2 += __shfl_xor(kn2, 32);
            float kn = sqrtf(kn2);
            #pragma unroll
            for (int d = 1; d < 16; d <<= 1) kn = fmaxf(kn, __shfl_xor(kn, d));
            if (lane == 0) atomicMax((int*)(kmax + b), __float_as_int(kn));
        }
    }

    asm volatile("s_waitcnt vmcnt(0)" ::: "memory");
    __builtin_amdgcn_s_barrier();
    asm volatile("" ::: "memory");

    const int jj = wq * 16 + li;
    const int p = ((jj >> 5) & 1) * 8 + ((jj >> 3) & 3) * 16 + (jj & 7);
    u8* vtile = Vg + (size_t)(b * NJT + nt) * 16384;
    const int vg = w >> 2;
    {
        const int r0 = vg * 32;
        f32x4 a[2] = {zero, zero};
        #pragma unroll
        for (int ks = 0; ks < 8; ++ks) {
            const int o = (ks * 64 + 16 * g) ^ swz;
            #pragma unroll
            for (int fr = 0; fr < 2; ++fr) {
                bf16x8 wf = *(const bf16x8*)(FW + (size_t)(r0 + fr * 16 + li) * 512 + o);
                a[fr] = MFMA16(wf, xf[ks], a[fr]);
            }
        }
        #pragma unroll
        for (int fr = 0; fr < 2; ++fr) {
            f32x4 bb = *(const f32x4*)(bv + r0 + fr * 16 + 4 * g);
            #pragma unroll
            for (int r = 0; r < 4; ++r) {
                const int c = r0 + fr * 16 + 4 * g + r;
                __builtin_nontemporal_store(f2fp8(a[fr][r] + bb[r]),
                    vtile + c * 64 + (p ^ (((c >> 1) & 3) << 4)));
            }
        }
    }

    __syncthreads();
    #pragma unroll
    for (int k = 0; k < 4; ++k)
        dma16(Wvb + 65536 + k * 16384 + t * 16, FW + k * 16384 + w * 1024);
    asm volatile("s_waitcnt vmcnt(0)" ::: "memory");
    __syncthreads();
    {
        const int r0v = 128 + vg * 32;
        const int r0l = vg * 32;
        f32x4 a[2] = {zero, zero};
        #pragma unroll
        for (int ks = 0; ks < 8; ++ks) {
            const int o = (ks * 64 + 16 * g) ^ swz;
            #pragma unroll
            for (int fr = 0; fr < 2; ++fr) {
                bf16x8 wf = *(const bf16x8*)(FW + (size_t)(r0l + fr * 16 + li) * 512 + o);
                a[fr] = MFMA16(wf, xf[ks], a[fr]);
            }
        }
        #pragma unroll
        for (int fr = 0; fr < 2; ++fr) {
            f32x4 bb = *(const f32x4*)(bv + r0v + fr * 16 + 4 * g);
            #pragma unroll
            for (int r = 0; r < 4; ++r) {
                const int c = r0v + fr * 16 + 4 * g + r;
                __builtin_nontemporal_store(f2fp8(a[fr][r] + bb[r]),
                    vtile + c * 64 + (p ^ (((c >> 1) & 3) << 4)));
            }
        }
    }
}

// ---------------------------------------------------------------------------
// Attention (R19, verified): 196 blocks x 1024 thr (16 waves), ONE barrier
// per j-tile; PV(it-1) + S(it) share the barrier region; ring-4 V/K depth-2.
// ---------------------------------------------------------------------------
__global__ __launch_bounds__(1024) void attn_mfma(
    const u16* __restrict__ qT, const u8* __restrict__ Kg,
    const u8* __restrict__ Vg, const float* __restrict__ x,
    const float* __restrict__ gamma_p, const float* __restrict__ qnorm,
    const float* __restrict__ kmax, float* __restrict__ out)
{
    __shared__ __align__(16) u8 smem[90112];
    u8* const Vl = smem;             // 4 x 16384
    u8* const Kl = smem + 65536;     // 4 x 4096
    u8* const Pl = smem + 81920;     // 2 x 4096 dbuf (reduce overlays after)

    const int t = threadIdx.x;
    const int w = t >> 6, li = t & 15, g = (t >> 4) & 3;
    const int jh = w & 3, qh = w >> 2;
    const int swz = ((li >> 1) & 3) << 4;

    const int b  = blockIdx.x / NJT;
    const int qt = blockIdx.x % NJT;
    const int i0 = qt * QT;

    const u16* qTb = qT + (size_t)b * N_SP * CQ;
    const u8*  Kbb = Kg + (size_t)b * N_SP * 64;
    const u8*  Vbb = Vg + (size_t)b * NJT * 16384;
    const float kmb = kmax[b];
    const f32x4 zero = {0.f, 0.f, 0.f, 0.f};

    const bf16x8 qf = *(const bf16x8*)(qTb + (size_t)(i0 + qh * 16 + li) * CQ + 8 * g);
    const float  mr = qnorm[b * N_SP + i0 + qh * 16 + li] * kmb;

    f32x4 acc[4];
    #pragma unroll
    for (int qq = 0; qq < 4; ++qq) acc[qq] = zero;
    float ls = 0.f;

    #define ISSUE(jt_, s_) do {                                               \
        dma16(Vbb + (size_t)(jt_) * 16384 + t * 16,                           \
              Vl + (s_) * 16384 + w * 1024);                                  \
        if (t < 256)                                                          \
            dma16(Kbb + (size_t)(jt_) * 4096 + t * 16,                        \
                  Kl + (s_) * 4096 + w * 1024);                               \
    } while (0)

    #define SPHASE(it_) do {                                                  \
        const u8* Kc_ = Kl + ((it_) & 3) * 4096;                              \
        bf16x8 kf_ = *(const bf16x8*)(Kc_ + (jh * 16 + li) * 64 + ((16 * g) ^ swz)); \
        f32x4 s_ = MFMA16(kf_, qf, zero);                                     \
        float a0_ = exp2f(s_[0] - mr), a1_ = exp2f(s_[1] - mr);               \
        float a2_ = exp2f(s_[2] - mr), a3_ = exp2f(s_[3] - mr);               \
        ls += (a0_ + a1_) + (a2_ + a3_);                                      \
        int pk_ = __builtin_amdgcn_cvt_pk_bf8_f32(a0_, a1_, 0, false);        \
        pk_ = __builtin_amdgcn_cvt_pk_bf8_f32(a2_, a3_, pk_, true);           \
        *(u32*)(Pl + ((it_) & 1) * 4096 + (qh * 16 + li) * 64 + (p0 ^ swz)) = (u32)pk_; \
    } while (0)

    #define PVPHASE(it_) do {                                                 \
        const u8* Pp_ = Pl + ((it_) & 1) * 4096;                              \
        const u8* Vc_ = Vl + ((it_) & 3) * 16384;                             \
        __builtin_amdgcn_s_setprio(1);                                        \
        l64x2 pa0_ = *(const l64x2*)(Pp_ + (0 * 16 + li) * 64 + ((16 * g) ^ swz)); \
        l64x2 pa1_ = *(const l64x2*)(Pp_ + (1 * 16 + li) * 64 + ((16 * g) ^ swz)); \
        l64x2 pa2_ = *(const l64x2*)(Pp_ + (2 * 16 + li) * 64 + ((16 * g) ^ swz)); \
        l64x2 pa3_ = *(const l64x2*)(Pp_ + (3 * 16 + li) * 64 + ((16 * g) ^ swz)); \
        l64x2 v0_  = *(const l64x2*)(Vc_ + (w * 16 + li) * 64 + ((16 * g) ^ swz)); \
        acc[0] = MFMA8(pa0_[0], v0_[0], acc[0]);                              \
        acc[1] = MFMA8(pa1_[0], v0_[0], acc[1]);                              \
        acc[2] = MFMA8(pa2_[0], v0_[0], acc[2]);                              \
        acc[3] = MFMA8(pa3_[0], v0_[0], acc[3]);                              \
        acc[0] = MFMA8(pa0_[1], v0_[1], acc[0]);                              \
        acc[1] = MFMA8(pa1_[1], v0_[1], acc[1]);                              \
        acc[2] = MFMA8(pa2_[1], v0_[1], acc[2]);                              \
        acc[3] = MFMA8(pa3_[1], v0_[1], acc[3]);                              \
        __builtin_amdgcn_s_setprio(0);                                        \
    } while (0)

    ISSUE(0, 0);
    ISSUE(1, 1);

    const int p0 = ((jh >> 1) & 1) * 8 + ((jh * 2 + (g >> 1)) & 3) * 16 + 4 * (g & 1);

    if (w < 4) asm volatile("s_waitcnt vmcnt(2) lgkmcnt(0)" ::: "memory");
    else       asm volatile("s_waitcnt vmcnt(1) lgkmcnt(0)" ::: "memory");
    __builtin_amdgcn_s_barrier();
    asm volatile("" ::: "memory");
    ISSUE(2, 2);
    SPHASE(0);

    for (int it = 1; it < NJT; ++it) {
        if (w < 4) asm volatile("s_waitcnt vmcnt(2) lgkmcnt(0)" ::: "memory");
        else       asm volatile("s_waitcnt vmcnt(1) lgkmcnt(0)" ::: "memory");
        __builtin_amdgcn_s_barrier();
        asm volatile("" ::: "memory");
        {
            int jn = it + 2; if (jn > NJT - 1) jn = NJT - 1;
            ISSUE(jn, (it + 2) & 3);
        }
        PVPHASE(it - 1);
        SPHASE(it);
    }

    asm volatile("s_waitcnt lgkmcnt(0)" ::: "memory");
    __builtin_amdgcn_s_barrier();
    asm volatile("" ::: "memory");
    PVPHASE(NJT - 1);
    #undef ISSUE
    #undef SPHASE
    #undef PVPHASE

    ls += __shfl_xor(ls, 16); ls += __shfl_xor(ls, 32);
    __syncthreads();
    float* red       = (float*)Pl;
    float* red_final = (float*)(Pl + 1024);
    if ((t & 63) < 16) red[w * 16 + li] = ls;
    __syncthreads();
    if (t < 64) {
        const int qh2 = t >> 4, l2 = t & 15;
        float s = red[(qh2 * 4 + 0) * 16 + l2] + red[(qh2 * 4 + 1) * 16 + l2]
                + red[(qh2 * 4 + 2) * 16 + l2] + red[(qh2 * 4 + 3) * 16 + l2];
        red_final[t] = s;
    }
    __syncthreads();

    const float gsc = gamma_p[0] * INV_BOUND;
    const int c = w * 16 + li;
    #pragma unroll
    for (int qq = 0; qq < 4; ++qq) {
        f32x4 lsv = *(const f32x4*)(red_final + qq * 16 + 4 * g);
        f32x4 rinv;
        #pragma unroll
        for (int r = 0; r < 4; ++r) rinv[r] = gsc / lsv[r];
        const size_t base = ((size_t)b * C_CH + c) * N_SP + i0 + qq * 16 + 4 * g;
        float4 xv = *(const float4*)(x + base);
        float4 o;
        o.x = acc[qq][0] * rinv[0] + xv.x;
        o.y = acc[qq][1] * rinv[1] + xv.y;
        o.z = acc[qq][2] * rinv[2] + xv.z;
        o.w = acc[qq][3] * rinv[3] + xv.w;
        *(float4*)(out + base) = o;
    }
}

// ---------------------------------------------------------------------------
extern "C" void kernel_launch(void* const* d_in, const int* in_sizes, int n_in,
                              void* d_out, int out_size, void* d_ws, size_t ws_size,
                              hipStream_t stream)
{
    const float* x  = (const float*)d_in[0];
    const float* Wq = (const float*)d_in[1];
    const float* bq = (const float*)d_in[2];
    const float* Wk = (const float*)d_in[3];
    const float* bk = (const float*)d_in[4];
    const float* Wv = (const float*)d_in[5];
    const float* bv = (const float*)d_in[6];
    const float* gm = (const float*)d_in[7];
    float* out = (float*)d_out;
    float* ws  = (float*)d_ws;

    float* scale = ws;                       // [0..3]
    float* kmax  = ws + 4;                   // [4..7]
    float* qnorm = ws + 8;                   // NB*N_SP
    u8* Wqb = (u8*)(ws + 8 + NB * N_SP);     // 16B-aligned
    u8* Wkb = Wqb + 32 * 512;
    u8* Wvb = Wkb + 32 * 512;
    u16* qT = (u16*)(Wvb + 256 * 512);
    u8* Kg  = (u8*)(qT + (size_t)NB * N_SP * CQ);
    u8* Vg  = Kg + (size_t)NB * N_SP * 64;

    stage0_kernel<<<81, 256, 0, stream>>>(Wq, Wk, Wv, Wqb, Wkb, Wvb, scale, kmax);
    qkv_fused<<<NB * NJT, 1024, 0, stream>>>(x, Wqb, Wkb, Wvb, bq, bk, bv, scale, qT, Kg, Vg, qnorm, kmax);
    attn_mfma<<<NB * NJT, 1024, 0, stream>>>(qT, Kg, Vg, x, gm, qnorm, kmax, out);
}

// Round 23
// 79.771 us; speedup vs baseline: 1.0145x; 1.0145x over previous
//
#include <hip/hip_runtime.h>

#define N_SP 3136   // H*W = 49*64
#define C_CH 256
#define CQ   32
#define NB   4
#define JT   64     // attn j-tile
#define NJT  49     // j-tiles (exact)
#define QT   64     // attn q-tile (49 tiles exact)
// 1 / (exp(sqrt(3))*sqrt(3136/256) + 2*sqrt(6))
#define INV_BOUND 0.04051569f
#define LOG2E 1.44269504f

typedef __attribute__((ext_vector_type(8))) short bf16x8;
typedef __attribute__((ext_vector_type(4))) float f32x4;
typedef __attribute__((ext_vector_type(2))) long long l64x2;
typedef unsigned short u16;
typedef unsigned int   u32;
typedef unsigned char  u8;
typedef long long      l64;

#define MFMA16(a,b,c) __builtin_amdgcn_mfma_f32_16x16x32_bf16(a,b,c,0,0,0)
#define MFMA8(a,b,c)  __builtin_amdgcn_mfma_f32_16x16x32_bf8_fp8(a,b,c,0,0,0)

__device__ __forceinline__ u16 f2b(float f) {
    u32 u = __builtin_bit_cast(u32, f);
    u += 0x7fffu + ((u >> 16) & 1u);   // RTNE
    return (u16)(u >> 16);
}
__device__ __forceinline__ u8 f2fp8(float f) {
    return (u8)(__builtin_amdgcn_cvt_pk_fp8_f32(f, f, 0, false) & 0xff);
}
__device__ __forceinline__ void dma16(const void* g, void* l) {
    __builtin_amdgcn_global_load_lds((const __attribute__((address_space(1))) u32*)g,
                                     (__attribute__((address_space(3))) u32*)l, 16, 0, 0);
}

// ---------------------------------------------------------------------------
// stage0: W->bf16 pre-swizzled (blocks 0..79), norm+scale+kmax0 (block 80)
// ---------------------------------------------------------------------------
__global__ __launch_bounds__(256) void stage0_kernel(
    const float* __restrict__ Wq, const float* __restrict__ Wk,
    const float* __restrict__ Wv, u8* __restrict__ Wqb,
    u8* __restrict__ Wkb, u8* __restrict__ Wvb,
    float* __restrict__ scale_out, float* __restrict__ kmax)
{
    __shared__ float red[256];
    const int t = threadIdx.x;
    const int bid = blockIdx.x;

    if (bid < 80) {
        int idx = bid * 256 + t;
        const float* src; u8* dst; int off;
        if (idx < 2048)      { src = Wq; dst = Wqb; off = idx; }
        else if (idx < 4096) { src = Wk; dst = Wkb; off = idx - 2048; }
        else                 { src = Wv; dst = Wvb; off = idx - 4096; }
        float4 v = *(const float4*)(src + off * 4);
        ushort4 o; o.x = f2b(v.x); o.y = f2b(v.y); o.z = f2b(v.z); o.w = f2b(v.w);
        const int row = off >> 6, inner = (off & 63) * 8;
        *(ushort4*)(dst + row * 512 + (inner ^ ((row & 15) << 5))) = o;
    } else {
        if (t < NB) kmax[t] = 0.f;
        float u2 = 0.f;
        for (int i = t; i < CQ * C_CH; i += 256) { float w = Wq[i]; u2 += w * w; }
        red[t] = u2; __syncthreads();
        #pragma unroll
        for (int s = 128; s > 0; s >>= 1) { if (t < s) red[t] += red[t + s]; __syncthreads(); }
        float u2t = red[0]; __syncthreads();
        float vn2 = 0.f;
        for (int o = 0; o < CQ; ++o)   { float w = Wk[o * C_CH + t]; vn2 += w * w; }
        float wn2 = 0.f;
        for (int o = 0; o < C_CH; ++o) { float w = Wv[o * C_CH + t]; wn2 += w * w; }
        red[t] = fmaxf(vn2, wn2); __syncthreads();
        #pragma unroll
        for (int s = 128; s > 0; s >>= 1) { if (t < s) red[t] = fmaxf(red[t], red[t + s]); __syncthreads(); }
        if (t == 0) scale_out[0] = 1.0f / (sqrtf(u2t) * sqrtf(red[0]));
    }
}

// ---------------------------------------------------------------------------
// qkv_fused (R21, verified at 79.7us total): 196 blocks (b, nt) x 1024 thr.
//  Phase A: transpose x-tile [256c][64n] -- all 4 slabs concurrently via 4
//           f32 staging tiles (2 barriers); x read once from HBM.
//  DMA overlap: W0 (Wq|Wk) in flight during transpose; Wv[0:128] issued into
//  the dead ftile region during q/k; Wv[128:256] ping-pongs the same region.
//  q/k: waves 0-7. V: 16 waves, 2 frags each.
// ---------------------------------------------------------------------------
__global__ __launch_bounds__(1024) void qkv_fused(
    const float* __restrict__ x, const u8* __restrict__ Wqb,
    const u8* __restrict__ Wkb, const u8* __restrict__ Wvb,
    const float* __restrict__ bq, const float* __restrict__ bk,
    const float* __restrict__ bv, const float* __restrict__ scale_p,
    u16* __restrict__ qT, u8* __restrict__ Kg, u8* __restrict__ Vg,
    float* __restrict__ qnorm, float* __restrict__ kmax)
{
    __shared__ __align__(16) u8 smem[132096];
    u8* const xTl = smem;                          // 32768: [64n][512B] swizzled
    u8* const FW  = smem + 32768;                  // 66560: ftile[4] -> Wv half
    u8* const W0  = smem + 99328;                  // 32768: Wq|Wk

    const int t = threadIdx.x;
    const int w = t >> 6, lane = t & 63, li = t & 15, g = (t >> 4) & 3;
    const int wq = w & 3;                          // n-group for compute
    const int b  = blockIdx.x / NJT;
    const int nt = blockIdx.x % NJT;
    const int n0 = nt * 64;
    const f32x4 zero = {0.f, 0.f, 0.f, 0.f};

    // ---- issue W0 (Wq|Wk, 32K): 2 dma16 per thread (uniform) ----
    #pragma unroll
    for (int k = 0; k < 2; ++k)
        dma16((k == 0 ? Wqb : Wkb) + t * 16, W0 + k * 16384 + w * 1024);

    // ---- Phase A: transpose 4 slabs concurrently ----
    {
        const int sl = t >> 8, tt = t & 255;
        const int c0 = sl * 64;
        float* ftile = (float*)(FW + sl * 16640);  // [64][65]
        const int cc = tt >> 4, nn4 = (tt & 15) * 4;
        #pragma unroll
        for (int k = 0; k < 4; ++k) {
            int cl = cc + k * 16;
            float4 v = *(const float4*)(x + (size_t)(b * C_CH + c0 + cl) * N_SP + n0 + nn4);
            ftile[cl * 65 + nn4]     = v.x;
            ftile[cl * 65 + nn4 + 1] = v.y;
            ftile[cl * 65 + nn4 + 2] = v.z;
            ftile[cl * 65 + nn4 + 3] = v.w;
        }
        __syncthreads();
        const int c4 = (tt & 15) * 4, nn = tt >> 4;
        #pragma unroll
        for (int k = 0; k < 4; ++k) {
            int nl = nn + k * 16;
            ushort4 o;
            o.x = f2b(ftile[(c4 + 0) * 65 + nl]);
            o.y = f2b(ftile[(c4 + 1) * 65 + nl]);
            o.z = f2b(ftile[(c4 + 2) * 65 + nl]);
            o.w = f2b(ftile[(c4 + 3) * 65 + nl]);
            *(ushort4*)(xTl + nl * 512 + (((c0 + c4) * 2) ^ ((nl & 15) << 5))) = o;
        }
    }
    __syncthreads();                               // ftile dead; xTl complete

    // ---- issue Wv[0:128] (64K) into FW: 4 dma16 per thread (uniform) ----
    #pragma unroll
    for (int k = 0; k < 4; ++k)
        dma16(Wvb + k * 16384 + t * 16, FW + k * 16384 + w * 1024);

    const int swz = li << 5;
    const int n = n0 + wq * 16 + li;
    bf16x8 xf[8];
    #pragma unroll
    for (int ks = 0; ks < 8; ++ks)
        xf[ks] = *(const bf16x8*)(xTl + (wq * 16 + li) * 512 + ((ks * 64 + 16 * g) ^ swz));

    // ---- q/k on waves 0-7 (W0 arrived: wait the 4 outstanding Wv DMAs) ----
    asm volatile("s_waitcnt vmcnt(4) lgkmcnt(0)" ::: "memory");
    __builtin_amdgcn_s_barrier();
    asm volatile("" ::: "memory");

    const int wh = w >> 2;
    if (w < 8) {
        if (wh == 0) {
            f32x4 aq0 = zero, aq1 = zero;
            #pragma unroll
            for (int ks = 0; ks < 8; ++ks) {
                const int o = (ks * 64 + 16 * g) ^ swz;
                bf16x8 w0 = *(const bf16x8*)(W0 + li * 512 + o);
                bf16x8 w1 = *(const bf16x8*)(W0 + (16 + li) * 512 + o);
                aq0 = MFMA16(w0, xf[ks], aq0);
                aq1 = MFMA16(w1, xf[ks], aq1);
            }
            const float scf = scale_p[0] * LOG2E;
            f32x4 bq0 = *(const f32x4*)(bq + 4 * g);
            f32x4 bq1 = *(const f32x4*)(bq + 16 + 4 * g);
            float qn2 = 0.f;
            ushort4 s0, s1;
            #pragma unroll
            for (int r = 0; r < 4; ++r) {
                float q0 = (aq0[r] + bq0[r]) * scf;
                float q1 = (aq1[r] + bq1[r]) * scf;
                qn2 += q0 * q0 + q1 * q1;
                ((u16*)&s0)[r] = f2b(q0); ((u16*)&s1)[r] = f2b(q1);
            }
            *(ushort4*)(qT + (size_t)(b * N_SP + n) * CQ + 4 * g)      = s0;
            *(ushort4*)(qT + (size_t)(b * N_SP + n) * CQ + 16 + 4 * g) = s1;
            qn2 += __shfl_xor(qn2, 16); qn2 += __shfl_xor(qn2, 32);
            if (g == 0) qnorm[b * N_SP + n] = sqrtf(qn2);
        } else {
            f32x4 ak0 = zero, ak1 = zero;
            #pragma unroll
            for (int ks = 0; ks < 8; ++ks) {
                const int o = (ks * 64 + 16 * g) ^ swz;
                bf16x8 w2 = *(const bf16x8*)(W0 + 16384 + li * 512 + o);
                bf16x8 w3 = *(const bf16x8*)(W0 + 16384 + (16 + li) * 512 + o);
                ak0 = MFMA16(w2, xf[ks], ak0);
                ak1 = MFMA16(w3, xf[ks], ak1);
            }
            f32x4 bk0 = *(const f32x4*)(bk + 4 * g);
            f32x4 bk1 = *(const f32x4*)(bk + 16 + 4 * g);
            float kn2 = 0.f;
            ushort4 s0, s1;
            #pragma unroll
            for (int r = 0; r < 4; ++r) {
                float k0 = ak0[r] + bk0[r];
                float k1 = ak1[r] + bk1[r];
                kn2 += k0 * k0 + k1 * k1;
                ((u16*)&s0)[r] = f2b(k0); ((u16*)&s1)[r] = f2b(k1);
            }
            u8* krow = Kg + ((size_t)b * N_SP + n) * 64;
            const int swn = ((n >> 1) & 3) << 4;
            *(ushort4*)(krow + ((8 * g) ^ swn))      = s0;
            *(ushort4*)(krow + ((32 + 8 * g) ^ swn)) = s1;
            kn2 += __shfl_xor(kn2, 16); kn2 += __shfl_xor(kn2, 32);
            float kn = sqrtf(kn2);
            #pragma unroll
            for (int d = 1; d < 16; d <<= 1) kn = fmaxf(kn, __shfl_xor(kn, d));
            if (lane == 0) atomicMax((int*)(kmax + b), __float_as_int(kn));
        }
    }

    // ---- V rows 0..127 on 16 waves (wait Wv0) ----
    asm volatile("s_waitcnt vmcnt(0)" ::: "memory");
    __builtin_amdgcn_s_barrier();
    asm volatile("" ::: "memory");

    const int jj = wq * 16 + li;
    const int p = ((jj >> 5) & 1) * 8 + ((jj >> 3) & 3) * 16 + (jj & 7);
    u8* vtile = Vg + (size_t)(b * NJT + nt) * 16384;
    const int vg = w >> 2;                         // 0..3: 32-row group
    {
        const int r0 = vg * 32;                    // rows in [0,128)
        f32x4 a[2] = {zero, zero};
        #pragma unroll
        for (int ks = 0; ks < 8; ++ks) {
            const int o = (ks * 64 + 16 * g) ^ swz;
            #pragma unroll
            for (int fr = 0; fr < 2; ++fr) {
                bf16x8 wf = *(const bf16x8*)(FW + (size_t)(r0 + fr * 16 + li) * 512 + o);
                a[fr] = MFMA16(wf, xf[ks], a[fr]);
            }
        }
        #pragma unroll
        for (int fr = 0; fr < 2; ++fr) {
            f32x4 bb = *(const f32x4*)(bv + r0 + fr * 16 + 4 * g);
            #pragma unroll
            for (int r = 0; r < 4; ++r) {
                const int c = r0 + fr * 16 + 4 * g + r;
                vtile[c * 64 + (p ^ (((c >> 1) & 3) << 4))] = f2fp8(a[fr][r] + bb[r]);
            }
        }
    }

    // ---- swap to Wv[128:256], then V rows 128..255 ----
    __syncthreads();
    #pragma unroll
    for (int k = 0; k < 4; ++k)
        dma16(Wvb + 65536 + k * 16384 + t * 16, FW + k * 16384 + w * 1024);
    asm volatile("s_waitcnt vmcnt(0)" ::: "memory");
    __syncthreads();
    {
        const int r0v = 128 + vg * 32;             // global V row base
        const int r0l = vg * 32;                   // row base within FW
        f32x4 a[2] = {zero, zero};
        #pragma unroll
        for (int ks = 0; ks < 8; ++ks) {
            const int o = (ks * 64 + 16 * g) ^ swz;
            #pragma unroll
            for (int fr = 0; fr < 2; ++fr) {
                bf16x8 wf = *(const bf16x8*)(FW + (size_t)(r0l + fr * 16 + li) * 512 + o);
                a[fr] = MFMA16(wf, xf[ks], a[fr]);
            }
        }
        #pragma unroll
        for (int fr = 0; fr < 2; ++fr) {
            f32x4 bb = *(const f32x4*)(bv + r0v + fr * 16 + 4 * g);
            #pragma unroll
            for (int r = 0; r < 4; ++r) {
                const int c = r0v + fr * 16 + 4 * g + r;
                vtile[c * 64 + (p ^ (((c >> 1) & 3) << 4))] = f2fp8(a[fr][r] + bb[r]);
            }
        }
    }
}

// ---------------------------------------------------------------------------
// Attention (R19, verified): 196 blocks x 1024 thr (16 waves), ONE barrier
// per j-tile; PV(it-1) + S(it) share the barrier region; ring-4 V/K depth-2.
// ---------------------------------------------------------------------------
__global__ __launch_bounds__(1024) void attn_mfma(
    const u16* __restrict__ qT, const u8* __restrict__ Kg,
    const u8* __restrict__ Vg, const float* __restrict__ x,
    const float* __restrict__ gamma_p, const float* __restrict__ qnorm,
    const float* __restrict__ kmax, float* __restrict__ out)
{
    __shared__ __align__(16) u8 smem[90112];
    u8* const Vl = smem;             // 4 x 16384
    u8* const Kl = smem + 65536;     // 4 x 4096
    u8* const Pl = smem + 81920;     // 2 x 4096 dbuf (reduce overlays after)

    const int t = threadIdx.x;
    const int w = t >> 6, li = t & 15, g = (t >> 4) & 3;
    const int jh = w & 3, qh = w >> 2;
    const int swz = ((li >> 1) & 3) << 4;

    const int b  = blockIdx.x / NJT;
    const int qt = blockIdx.x % NJT;
    const int i0 = qt * QT;

    const u16* qTb = qT + (size_t)b * N_SP * CQ;
    const u8*  Kbb = Kg + (size_t)b * N_SP * 64;
    const u8*  Vbb = Vg + (size_t)b * NJT * 16384;
    const float kmb = kmax[b];
    const f32x4 zero = {0.f, 0.f, 0.f, 0.f};

    const bf16x8 qf = *(const bf16x8*)(qTb + (size_t)(i0 + qh * 16 + li) * CQ + 8 * g);
    const float  mr = qnorm[b * N_SP + i0 + qh * 16 + li] * kmb;

    f32x4 acc[4];
    #pragma unroll
    for (int qq = 0; qq < 4; ++qq) acc[qq] = zero;
    float ls = 0.f;

    #define ISSUE(jt_, s_) do {                                               \
        dma16(Vbb + (size_t)(jt_) * 16384 + t * 16,                           \
              Vl + (s_) * 16384 + w * 1024);                                  \
        if (t < 256)                                                          \
            dma16(Kbb + (size_t)(jt_) * 4096 + t * 16,                        \
                  Kl + (s_) * 4096 + w * 1024);                               \
    } while (0)

    #define SPHASE(it_) do {                                                  \
        const u8* Kc_ = Kl + ((it_) & 3) * 4096;                              \
        bf16x8 kf_ = *(const bf16x8*)(Kc_ + (jh * 16 + li) * 64 + ((16 * g) ^ swz)); \
        f32x4 s_ = MFMA16(kf_, qf, zero);                                     \
        float a0_ = exp2f(s_[0] - mr), a1_ = exp2f(s_[1] - mr);               \
        float a2_ = exp2f(s_[2] - mr), a3_ = exp2f(s_[3] - mr);               \
        ls += (a0_ + a1_) + (a2_ + a3_);                                      \
        int pk_ = __builtin_amdgcn_cvt_pk_bf8_f32(a0_, a1_, 0, false);        \
        pk_ = __builtin_amdgcn_cvt_pk_bf8_f32(a2_, a3_, pk_, true);           \
        *(u32*)(Pl + ((it_) & 1) * 4096 + (qh * 16 + li) * 64 + (p0 ^ swz)) = (u32)pk_; \
    } while (0)

    #define PVPHASE(it_) do {                                                 \
        const u8* Pp_ = Pl + ((it_) & 1) * 4096;                              \
        const u8* Vc_ = Vl + ((it_) & 3) * 16384;                             \
        __builtin_amdgcn_s_setprio(1);                                        \
        l64x2 pa0_ = *(const l64x2*)(Pp_ + (0 * 16 + li) * 64 + ((16 * g) ^ swz)); \
        l64x2 pa1_ = *(const l64x2*)(Pp_ + (1 * 16 + li) * 64 + ((16 * g) ^ swz)); \
        l64x2 pa2_ = *(const l64x2*)(Pp_ + (2 * 16 + li) * 64 + ((16 * g) ^ swz)); \
        l64x2 pa3_ = *(const l64x2*)(Pp_ + (3 * 16 + li) * 64 + ((16 * g) ^ swz)); \
        l64x2 v0_  = *(const l64x2*)(Vc_ + (w * 16 + li) * 64 + ((16 * g) ^ swz)); \
        acc[0] = MFMA8(pa0_[0], v0_[0], acc[0]);                              \
        acc[1] = MFMA8(pa1_[0], v0_[0], acc[1]);                              \
        acc[2] = MFMA8(pa2_[0], v0_[0], acc[2]);                              \
        acc[3] = MFMA8(pa3_[0], v0_[0], acc[3]);                              \
        acc[0] = MFMA8(pa0_[1], v0_[1], acc[0]);                              \
        acc[1] = MFMA8(pa1_[1], v0_[1], acc[1]);                              \
        acc[2] = MFMA8(pa2_[1], v0_[1], acc[2]);                              \
        acc[3] = MFMA8(pa3_[1], v0_[1], acc[3]);                              \
        __builtin_amdgcn_s_setprio(0);                                        \
    } while (0)

    ISSUE(0, 0);
    ISSUE(1, 1);

    const int p0 = ((jh >> 1) & 1) * 8 + ((jh * 2 + (g >> 1)) & 3) * 16 + 4 * (g & 1);

    if (w < 4) asm volatile("s_waitcnt vmcnt(2) lgkmcnt(0)" ::: "memory");
    else       asm volatile("s_waitcnt vmcnt(1) lgkmcnt(0)" ::: "memory");
    __builtin_amdgcn_s_barrier();
    asm volatile("" ::: "memory");
    ISSUE(2, 2);
    SPHASE(0);

    for (int it = 1; it < NJT; ++it) {
        if (w < 4) asm volatile("s_waitcnt vmcnt(2) lgkmcnt(0)" ::: "memory");
        else       asm volatile("s_waitcnt vmcnt(1) lgkmcnt(0)" ::: "memory");
        __builtin_amdgcn_s_barrier();
        asm volatile("" ::: "memory");
        {
            int jn = it + 2; if (jn > NJT - 1) jn = NJT - 1;
            ISSUE(jn, (it + 2) & 3);
        }
        PVPHASE(it - 1);
        SPHASE(it);
    }

    asm volatile("s_waitcnt lgkmcnt(0)" ::: "memory");
    __builtin_amdgcn_s_barrier();
    asm volatile("" ::: "memory");
    PVPHASE(NJT - 1);
    #undef ISSUE
    #undef SPHASE
    #undef PVPHASE

    ls += __shfl_xor(ls, 16); ls += __shfl_xor(ls, 32);
    __syncthreads();
    float* red       = (float*)Pl;
    float* red_final = (float*)(Pl + 1024);
    if ((t & 63) < 16) red[w * 16 + li] = ls;
    __syncthreads();
    if (t < 64) {
        const int qh2 = t >> 4, l2 = t & 15;
        float s = red[(qh2 * 4 + 0) * 16 + l2] + red[(qh2 * 4 + 1) * 16 + l2]
                + red[(qh2 * 4 + 2) * 16 + l2] + red[(qh2 * 4 + 3) * 16 + l2];
        red_final[t] = s;
    }
    __syncthreads();

    const float gsc = gamma_p[0] * INV_BOUND;
    const int c = w * 16 + li;
    #pragma unroll
    for (int qq = 0; qq < 4; ++qq) {
        f32x4 lsv = *(const f32x4*)(red_final + qq * 16 + 4 * g);
        f32x4 rinv;
        #pragma unroll
        for (int r = 0; r < 4; ++r) rinv[r] = gsc / lsv[r];
        const size_t base = ((size_t)b * C_CH + c) * N_SP + i0 + qq * 16 + 4 * g;
        float4 xv = *(const float4*)(x + base);
        float4 o;
        o.x = acc[qq][0] * rinv[0] + xv.x;
        o.y = acc[qq][1] * rinv[1] + xv.y;
        o.z = acc[qq][2] * rinv[2] + xv.z;
        o.w = acc[qq][3] * rinv[3] + xv.w;
        *(float4*)(out + base) = o;
    }
}

// ---------------------------------------------------------------------------
extern "C" void kernel_launch(void* const* d_in, const int* in_sizes, int n_in,
                              void* d_out, int out_size, void* d_ws, size_t ws_size,
                              hipStream_t stream)
{
    const float* x  = (const float*)d_in[0];
    const float* Wq = (const float*)d_in[1];
    const float* bq = (const float*)d_in[2];
    const float* Wk = (const float*)d_in[3];
    const float* bk = (const float*)d_in[4];
    const float* Wv = (const float*)d_in[5];
    const float* bv = (const float*)d_in[6];
    const float* gm = (const float*)d_in[7];
    float* out = (float*)d_out;
    float* ws  = (float*)d_ws;

    float* scale = ws;                       // [0..3]
    float* kmax  = ws + 4;                   // [4..7]
    float* qnorm = ws + 8;                   // NB*N_SP
    u8* Wqb = (u8*)(ws + 8 + NB * N_SP);     // 16B-aligned
    u8* Wkb = Wqb + 32 * 512;
    u8* Wvb = Wkb + 32 * 512;
    u16* qT = (u16*)(Wvb + 256 * 512);
    u8* Kg  = (u8*)(qT + (size_t)NB * N_SP * CQ);
    u8* Vg  = Kg + (size_t)NB * N_SP * 64;

    stage0_kernel<<<81, 256, 0, stream>>>(Wq, Wk, Wv, Wqb, Wkb, Wvb, scale, kmax);
    qkv_fused<<<NB * NJT, 1024, 0, stream>>>(x, Wqb, Wkb, Wvb, bq, bk, bv, scale, qT, Kg, Vg, qnorm, kmax);
    attn_mfma<<<NB * NJT, 1024, 0, stream>>>(qT, Kg, Vg, x, gm, qnorm, kmax, out);
}